// Round 12
// baseline (541.504 us; speedup 1.0000x reference)
//
#include <hip/hip_runtime.h>

// Depthwise 7x7 true-conv (flipped kernel, SAME zero pad) + mish, via MFMA
// with banded-Toeplitz B. Round-12: NO input staging, NO main-loop barriers.
// A-fragments load straight from global (L1 serves the 7x p-row reuse),
// cvt to f16 in-flight; B built once in LDS, bfrags hoisted to registers.
// Each wave owns 8 independent 16x64 tiles (block = half plane, grid 2048,
// 8 blocks/CU). Interior tiles: single base + imm-offset loads. Edge tiles:
// clamped addresses + value masking (wave-uniform branch).
//
// Math per 16x16 subtile, kernel row p:  C += A_p x B_p,
//   A_p[i,k] = f16(X[r0+i+p-3, c0-8+16t+k]), B_p[k,j] = W'[p][k-j-5],
//   W'[p][q] = kern[6-p][6-q].  C layout: col=lane&15, row=(lane>>4)*4+reg.

#define HW 256

typedef _Float16 f16x8 __attribute__((ext_vector_type(8)));
typedef float    f32x4 __attribute__((ext_vector_type(4)));
typedef __fp16   h2    __attribute__((ext_vector_type(2)));
union U32H2 { unsigned u; h2 h; };
union BFU   { uint4 u; f16x8 h; };

__device__ __forceinline__ float mish_f(float y) {
    float t = __expf(y);            // inf-safe: d -> inf -> 2/d -> 0 -> y*1
    float u = 1.0f + t;
    float d = __fmaf_rn(u, u, 1.0f);
    return y * (1.0f - __fdividef(2.0f, d));
}

__device__ __forceinline__ f16x8 cvt8(float4 f0, float4 f1, bool ok) {
    U32H2 a0, a1, a2, a3;
    a0.h = __builtin_amdgcn_cvt_pkrtz(f0.x, f0.y);
    a1.h = __builtin_amdgcn_cvt_pkrtz(f0.z, f0.w);
    a2.h = __builtin_amdgcn_cvt_pkrtz(f1.x, f1.y);
    a3.h = __builtin_amdgcn_cvt_pkrtz(f1.z, f1.w);
    BFU r;
    r.u = make_uint4(ok ? a0.u : 0u, ok ? a1.u : 0u,
                     ok ? a2.u : 0u, ok ? a3.u : 0u);
    return r.h;
}

__global__ __launch_bounds__(256)
__attribute__((amdgpu_waves_per_eu(6, 8)))
void dwconv7_mish_gdir(const float* __restrict__ x,
                       const float* __restrict__ kern,
                       float* __restrict__ out) {
    __shared__ __align__(16) unsigned lds_B[7 * 256];   // 7168 B only

    const int tid = threadIdx.x;
    const int bid = blockIdx.x;
    const int plane = bid >> 1;
    const int rbase = (bid & 1) << 7;        // 0 or 128

    const float* __restrict__ xp = x + (size_t)plane * (HW * HW);
    float* __restrict__ op = out + (size_t)plane * (HW * HW);

    // Flipped kernel in SGPRs: kf[p*7+q] = kern[6-p][6-q]
    float kf[49];
    #pragma unroll
    for (int i = 0; i < 49; ++i) {
        int p = i / 7, q = i - p * 7;
        kf[i] = __int_as_float(__builtin_amdgcn_readfirstlane(
                    __float_as_int(kern[(6 - p) * 7 + (6 - q)])));
    }

    // Banded-Toeplitz B_p[16][32] f16, word idx = p*256 + j*16 + k/2.
    {
        const int j  = tid >> 4;
        const int kw = tid & 15;
        #pragma unroll
        for (int p = 0; p < 7; ++p) {
            const int d0 = 2 * kw - j - 5;
            const int d1 = d0 + 1;
            float v0 = 0.f, v1 = 0.f;
            #pragma unroll
            for (int q = 0; q < 7; ++q) {
                v0 = (d0 == q) ? kf[p * 7 + q] : v0;
                v1 = (d1 == q) ? kf[p * 7 + q] : v1;
            }
            U32H2 u; u.h = __builtin_amdgcn_cvt_pkrtz(v0, v1);
            lds_B[p * 256 + tid] = u.u;
        }
    }
    __syncthreads();   // the ONLY barrier

    const int lane = tid & 63;
    const int w    = tid >> 6;
    const int lrow = lane & 15;
    const int lk   = lane >> 4;

    // Hoist B fragments into registers (28 VGPR): B[k=8lk+e, j=lrow].
    f16x8 bfrag[7];
    #pragma unroll
    for (int p = 0; p < 7; ++p) {
        BFU bu;
        bu.u = ((const uint4*)lds_B)[(p << 6) + (lrow << 2) + lk];
        bfrag[p] = bu.h;
    }

    // 8 tiles per wave: cols sweep fastest (right-halo L1 reuse).
    #pragma unroll 1
    for (int s = 0; s < 8; ++s) {
        const int c0 = (s & 3) << 6;
        const int r0 = rbase + (w << 4) + ((s >> 2) << 6);

        f32x4 acc[4];
        #pragma unroll
        for (int t = 0; t < 4; ++t) acc[t] = (f32x4){0.f, 0.f, 0.f, 0.f};

        const bool interior = (r0 >= 16) && (r0 <= 224) &&
                              (c0 >= 64) && (c0 <= 128);
        if (interior) {
            // one base + imm offsets: p*1024 + t*64 (+16) bytes, all < 8 KB
            const float* base = xp + (r0 + lrow - 3) * HW + (c0 + (lk << 3) - 8);
            #pragma unroll
            for (int p = 0; p < 7; ++p) {
                const float* rp = base + p * HW;
                #pragma unroll
                for (int t = 0; t < 4; ++t) {
                    float4 f0 = *(const float4*)(rp + 16 * t);
                    float4 f1 = *(const float4*)(rp + 16 * t + 4);
                    acc[t] = __builtin_amdgcn_mfma_f32_16x16x32_f16(
                                 cvt8(f0, f1, true), bfrag[p], acc[t], 0, 0, 0);
                }
            }
        } else {
            #pragma unroll
            for (int p = 0; p < 7; ++p) {
                const int gr  = r0 + lrow + p - 3;
                const bool rok = (unsigned)gr < (unsigned)HW;
                const int grc = gr < 0 ? 0 : (gr > HW - 1 ? HW - 1 : gr);
                const float* rp = xp + grc * HW;
                #pragma unroll
                for (int t = 0; t < 4; ++t) {
                    const int gc  = c0 + (t << 4) + (lk << 3) - 8;
                    const bool cok = (unsigned)gc <= (unsigned)(HW - 8);
                    const int gcc = gc < 0 ? 0 : (gc > HW - 8 ? HW - 8 : gc);
                    float4 f0 = *(const float4*)(rp + gcc);
                    float4 f1 = *(const float4*)(rp + gcc + 4);
                    acc[t] = __builtin_amdgcn_mfma_f32_16x16x32_f16(
                                 cvt8(f0, f1, rok && cok), bfrag[p], acc[t],
                                 0, 0, 0);
                }
            }
        }

        // Epilogue: mish + stores (wave writes 4 dense 64B row-chunks/inst).
        #pragma unroll
        for (int t = 0; t < 4; ++t) {
            const int col = c0 + (t << 4) + lrow;
            const int rb2 = r0 + (lk << 2);
            op[(rb2 + 0) * HW + col] = mish_f(acc[t][0]);
            op[(rb2 + 1) * HW + col] = mish_f(acc[t][1]);
            op[(rb2 + 2) * HW + col] = mish_f(acc[t][2]);
            op[(rb2 + 3) * HW + col] = mish_f(acc[t][3]);
        }
    }
}

extern "C" void kernel_launch(void* const* d_in, const int* in_sizes, int n_in,
                              void* d_out, int out_size, void* d_ws, size_t ws_size,
                              hipStream_t stream) {
    const float* x = (const float*)d_in[0];
    const float* k = (const float*)d_in[1];
    float* out = (float*)d_out;

    dim3 grid(2 * 16 * 64, 1, 1);   // 2048 blocks = 2 per plane, 8/CU
    dim3 block(256);
    dwconv7_mish_gdir<<<grid, block, 0, stream>>>(x, k, out);
}

// Round 13
// 132.643 us; speedup vs baseline: 4.0824x; 4.0824x over previous
//
#include <hip/hip_runtime.h>

// Depthwise 7x7 true-convolution (flipped kernel, SAME zero pad) + mish,
// via MFMA (v_mfma_f32_16x16x32_f16) with banded-Toeplitz weight matrices.
// Round-13 = round-11 with a TRUE async-stage split (T14):
//   step 1: issue tile t+1's global float4 loads RAW (no cvt -> no vmcnt
//           wait before compute; results live in 24 VGPRs)
//   step 2: compute tile t from lds_in[t&1] (28 MFMA + mish + stores)
//   step 3: s_waitcnt vmcnt (compiler-inserted at first use), cvt_pkrtz,
//           ds_write into lds_in[(t+1)&1]
//   step 4: one __syncthreads per tile
// sched_barrier(0) fences both sides of step 2 so the compiler cannot hoist
// step 3's cvt (and its vmcnt wait) above the MFMAs to shed register
// pressure (round-11's hidden serialization).
//
// Math per 16x16 output subtile, kernel row p:
//   C[i,j] += A_p[i,:] x B_p[:,j],  A_p[i,k] = Xf16[r0+i+p-3, c0-8+16t+k],
//   B_p[k,j] = W'[p][k-j-5] (banded), W'[p][q] = kern[6-p][6-q].
// MFMA C layout (m89): col = lane&15, row = (lane>>4)*4 + reg.

#define HW 256
#define PITCH 88           // halfs per LDS input row
#define LROWS 70           // 64 + 6 halo
#define NSTG 1400          // 70 rows * 20 float4 granules
#define TPB 8              // tiles per block (half a plane)

typedef _Float16 f16x8 __attribute__((ext_vector_type(8)));
typedef float    f32x4 __attribute__((ext_vector_type(4)));
typedef __fp16   h2    __attribute__((ext_vector_type(2)));
union U32H2 { unsigned u; h2 h; };
union BFU   { uint4 u; f16x8 h; };

__device__ __forceinline__ float mish_f(float y) {
    float t = __expf(y);            // inf-safe: d -> inf -> 2/d -> 0 -> y*1
    float u = 1.0f + t;
    float d = __fmaf_rn(u, u, 1.0f);
    return y * (1.0f - __fdividef(2.0f, d));
}

__global__ __launch_bounds__(256)
__attribute__((amdgpu_waves_per_eu(3, 5)))
void dwconv7_mish_mfma3(const float* __restrict__ x,
                        const float* __restrict__ kern,
                        float* __restrict__ out) {
    __shared__ __align__(16) _Float16 lds_in[2][LROWS * PITCH]; // 2 x 12320 B
    __shared__ __align__(16) unsigned lds_B[7 * 256];           // 7168 B

    const int tid = threadIdx.x;
    const int bid = blockIdx.x;
    const int plane = bid >> 1;          // 2 blocks per plane
    const int sbase = (bid & 1) << 3;    // tile slot: c0=(s&3)*64, r0=(s>>2)*64

    const float* __restrict__ xp = x + (size_t)plane * (HW * HW);
    float* __restrict__ op = out + (size_t)plane * (HW * HW);

    // Flipped kernel in SGPRs: kf[p*7+q] = kern[6-p][6-q]
    float kf[49];
    #pragma unroll
    for (int i = 0; i < 49; ++i) {
        int p = i / 7, q = i - p * 7;
        kf[i] = __int_as_float(__builtin_amdgcn_readfirstlane(
                    __float_as_int(kern[(6 - p) * 7 + (6 - q)])));
    }

    // Banded-Toeplitz B_p[16][32] f16, word idx = p*256 + j*16 + k/2.
    {
        const int j  = tid >> 4;
        const int kw = tid & 15;
        #pragma unroll
        for (int p = 0; p < 7; ++p) {
            const int d0 = 2 * kw - j - 5;
            const int d1 = d0 + 1;
            float v0 = 0.f, v1 = 0.f;
            #pragma unroll
            for (int q = 0; q < 7; ++q) {
                v0 = (d0 == q) ? kf[p * 7 + q] : v0;
                v1 = (d1 == q) ? kf[p * 7 + q] : v1;
            }
            U32H2 u; u.h = __builtin_amdgcn_cvt_pkrtz(v0, v1);
            lds_B[p * 256 + tid] = u.u;
        }
    }

    // Per-thread staging decomposition: idx = tid+256*it -> r=idx/20, g=idx%20.
    int ro_[6], co_[6], lo_[6];
    #pragma unroll
    for (int it = 0; it < 6; ++it) {
        int idx = tid + it * 256;
        int r = idx / 20, g = idx - 20 * r;
        ro_[it] = r - 3;
        co_[it] = 4 * g - 8;
        lo_[it] = r * 22 + g;
    }

    // Prologue: stage tile sbase into buf0 (immediate cvt is fine here).
    {
        const int c0 = (sbase & 3) << 6, r0 = (sbase >> 2) << 6;
        #pragma unroll
        for (int it = 0; it < 6; ++it) {
            if (it < 5 || tid < NSTG - 1280) {
                int gr = r0 + ro_[it], gc = c0 + co_[it];
                float4 f = make_float4(0.f, 0.f, 0.f, 0.f);
                if ((unsigned)gr < (unsigned)HW && (unsigned)gc <= (unsigned)(HW - 4))
                    f = *(const float4*)(xp + (gr << 8) + gc);
                U32H2 a, b;
                a.h = __builtin_amdgcn_cvt_pkrtz(f.x, f.y);
                b.h = __builtin_amdgcn_cvt_pkrtz(f.z, f.w);
                ((uint2*)lds_in[0])[lo_[it]] = make_uint2(a.u, b.u);
            }
        }
    }
    __syncthreads();

    const int lane = tid & 63;
    const int w    = tid >> 6;           // wave: tile rows 16w..16w+15
    const int lrow = lane & 15;
    const int lk   = lane >> 4;

    // B fragments hoisted: B[k=lk*8+e, j=lrow], contiguous 16 B per lane.
    f16x8 bfrag[7];
    #pragma unroll
    for (int p = 0; p < 7; ++p) {
        BFU bu;
        bu.u = ((const uint4*)lds_B)[p * 64 + lrow * 4 + lk];
        bfrag[p] = bu.h;
    }

    float4 rf[6];

    #pragma unroll 1
    for (int t = 0; t < TPB; ++t) {
        const int s  = sbase + t;
        const int c0 = (s & 3) << 6, r0 = (s >> 2) << 6;

        // ---- step 1: issue next tile's RAW loads (no consumption) ----
        if (t + 1 < TPB) {
            const int s2 = sbase + t + 1;
            const int c2 = (s2 & 3) << 6, r2 = (s2 >> 2) << 6;
            #pragma unroll
            for (int it = 0; it < 6; ++it) {
                if (it < 5 || tid < NSTG - 1280) {
                    int gr = r2 + ro_[it], gc = c2 + co_[it];
                    rf[it] = make_float4(0.f, 0.f, 0.f, 0.f);
                    if ((unsigned)gr < (unsigned)HW && (unsigned)gc <= (unsigned)(HW - 4))
                        rf[it] = *(const float4*)(xp + (gr << 8) + gc);
                }
            }
        }
        __builtin_amdgcn_sched_barrier(0);

        // ---- step 2: compute current tile from lds_in[t&1] ----
        const _Float16* bufp = lds_in[t & 1];
        #pragma unroll
        for (int t4 = 0; t4 < 4; ++t4) {
            f32x4 acc = {0.f, 0.f, 0.f, 0.f};
            #pragma unroll
            for (int p = 0; p < 7; ++p) {
                f16x8 a = *(const f16x8*)(bufp +
                            (16 * w + lrow + p) * PITCH + 16 * t4 + 8 * lk);
                acc = __builtin_amdgcn_mfma_f32_16x16x32_f16(a, bfrag[p], acc,
                                                             0, 0, 0);
            }
            const int col   = c0 + 16 * t4 + lrow;
            const int rbase = r0 + 16 * w + 4 * lk;
            op[(rbase + 0) * HW + col] = mish_f(acc[0]);
            op[(rbase + 1) * HW + col] = mish_f(acc[1]);
            op[(rbase + 2) * HW + col] = mish_f(acc[2]);
            op[(rbase + 3) * HW + col] = mish_f(acc[3]);
        }
        __builtin_amdgcn_sched_barrier(0);

        // ---- step 3: consume loads (vmcnt wait lands HERE), cvt, ds_write ----
        if (t + 1 < TPB) {
            #pragma unroll
            for (int it = 0; it < 6; ++it) {
                if (it < 5 || tid < NSTG - 1280) {
                    U32H2 a, b;
                    a.h = __builtin_amdgcn_cvt_pkrtz(rf[it].x, rf[it].y);
                    b.h = __builtin_amdgcn_cvt_pkrtz(rf[it].z, rf[it].w);
                    ((uint2*)lds_in[(t + 1) & 1])[lo_[it]] = make_uint2(a.u, b.u);
                }
            }
        }
        // ---- step 4: one barrier per tile ----
        __syncthreads();
    }
}

extern "C" void kernel_launch(void* const* d_in, const int* in_sizes, int n_in,
                              void* d_out, int out_size, void* d_ws, size_t ws_size,
                              hipStream_t stream) {
    const float* x = (const float*)d_in[0];
    const float* k = (const float*)d_in[1];
    float* out = (float*)d_out;

    dim3 grid(2 * 16 * 64, 1, 1);   // 2048 blocks: 2 per plane
    dim3 block(256);
    dwconv7_mish_mfma3<<<grid, block, 0, stream>>>(x, k, out);
}